// Round 1
// baseline (2314.619 us; speedup 1.0000x reference)
//
#include <hip/hip_runtime.h>

#define TT 2000
#define BB 128
#define DD 64
#define UU 128
#define G3U 384          // 3*U
#define NROW (BB * TT)   // 256000 rows of x / gx

// ---------- small helpers ----------
__device__ __forceinline__ float4 fma4(float s, float4 w, float4 a) {
  a.x = fmaf(s, w.x, a.x);
  a.y = fmaf(s, w.y, a.y);
  a.z = fmaf(s, w.z, a.z);
  a.w = fmaf(s, w.w, a.w);
  return a;
}
__device__ __forceinline__ float2 fma2(float s, float2 w, float2 a) {
  a.x = fmaf(s, w.x, a.x);
  a.y = fmaf(s, w.y, a.y);
  return a;
}
// sum across the 4 lanes of a quad via DPP quad_perm (VALU pipe, no LDS)
__device__ __forceinline__ float quad_sum(float v) {
  v += __int_as_float(__builtin_amdgcn_update_dpp(0, __float_as_int(v), 0xB1, 0xF, 0xF, true)); // swap lane^1
  v += __int_as_float(__builtin_amdgcn_update_dpp(0, __float_as_int(v), 0x4E, 0xF, 0xF, true)); // swap lane^2
  return v;
}
__device__ __forceinline__ float sigmoidf_(float v) { return 1.0f / (1.0f + __expf(-v)); }
__device__ __forceinline__ float tanhf_(float v) {
  float a = fabsf(v);
  float e = __expf(-2.0f * a);
  float r = (1.0f - e) / (1.0f + e);   // in [0,1), no NaN for large |v|
  return copysignf(r, v);
}

// ---------- prologue: gx[r][c] = sum_k x[r][k]*(kern[k][c]+akern[k][c]) + bias[c] ----------
// tiles: 64 rows x 64 cols, K = 64 (full D). 256 threads, 4x4 micro-tile each.
__global__ __launch_bounds__(256, 2)
void gx_kernel(const float* __restrict__ x, const float* __restrict__ kern,
               const float* __restrict__ akern, const float* __restrict__ bias,
               float* __restrict__ gx) {
  __shared__ __align__(16) float xT[64][68];  // transposed x tile, padded
  __shared__ __align__(16) float Ws[64][68];  // Wc tile, padded
  const int r0 = blockIdx.x * 64;
  const int c0 = blockIdx.y * 64;
  const int tid = threadIdx.x;

  {
    const int row = tid >> 2;          // 0..63
    const int kb = (tid & 3) * 16;     // 0,16,32,48
#pragma unroll
    for (int i = 0; i < 4; ++i) {
      float4 v = *(const float4*)&x[(size_t)(r0 + row) * DD + kb + i * 4];
      xT[kb + i * 4 + 0][row] = v.x;
      xT[kb + i * 4 + 1][row] = v.y;
      xT[kb + i * 4 + 2][row] = v.z;
      xT[kb + i * 4 + 3][row] = v.w;
    }
    const int kk = tid >> 2;           // 0..63 (k index)
    const int jb = (tid & 3) * 16;
#pragma unroll
    for (int i = 0; i < 4; ++i) {
      const size_t off = (size_t)kk * G3U + c0 + jb + i * 4;
      float4 a = *(const float4*)&kern[off];
      float4 c = *(const float4*)&akern[off];
      *(float4*)&Ws[kk][jb + i * 4] = make_float4(a.x + c.x, a.y + c.y, a.z + c.z, a.w + c.w);
    }
  }
  __syncthreads();

  const int tx = tid & 15, ty = tid >> 4;
  float4 acc0 = make_float4(0, 0, 0, 0), acc1 = acc0, acc2 = acc0, acc3 = acc0;
#pragma unroll
  for (int k = 0; k < 64; ++k) {
    float4 wv = *(const float4*)&Ws[k][tx * 4];
    float4 xv = *(const float4*)&xT[k][ty * 4];
    acc0 = fma4(xv.x, wv, acc0);
    acc1 = fma4(xv.y, wv, acc1);
    acc2 = fma4(xv.z, wv, acc2);
    acc3 = fma4(xv.w, wv, acc3);
  }
  float4 bv = *(const float4*)&bias[c0 + tx * 4];
  acc0.x += bv.x; acc0.y += bv.y; acc0.z += bv.z; acc0.w += bv.w;
  acc1.x += bv.x; acc1.y += bv.y; acc1.z += bv.z; acc1.w += bv.w;
  acc2.x += bv.x; acc2.y += bv.y; acc2.z += bv.z; acc2.w += bv.w;
  acc3.x += bv.x; acc3.y += bv.y; acc3.z += bv.z; acc3.w += bv.w;
  float* g0 = &gx[(size_t)(r0 + ty * 4) * G3U + c0 + tx * 4];
  *(float4*)(g0 + 0 * G3U) = acc0;
  *(float4*)(g0 + 1 * G3U) = acc1;
  *(float4*)(g0 + 2 * G3U) = acc2;
  *(float4*)(g0 + 3 * G3U) = acc3;
}

// ---------- recurrence: one block per batch row, persistent over T ----------
// 512 threads = 8 waves. waves 0-3: z/r gates (256 outputs, P=4, k-chunk 32)
//                        waves 4-7: hh candidate (128 outputs, P=2, k-chunk 32)
// quad structure: lane = ug*4 + kq ; kq = k-chunk, partials combined via DPP.
__global__ __launch_bounds__(512, 1)
void gru_rec(const float* __restrict__ gx, const float* __restrict__ rk,
             const float* __restrict__ h0, float* __restrict__ out) {
  const int b = blockIdx.x;
  const int tid = threadIdx.x;
  const int w = tid >> 6;
  const int l = tid & 63;
  const int ug = l >> 2;
  const int kq = l & 3;

  // chunked, bank-staggered buffers: value k lives at [k>>5][k&31]
  __shared__ __align__(16) float h_buf[4][40];
  __shared__ __align__(16) float rh_buf[4][40];
  __shared__ __align__(16) float zbuf[128];

  const float* gxb = gx + (size_t)b * TT * G3U;
  float* outb = out + (size_t)b * TT * UU;

  if (tid < 128) h_buf[tid >> 5][tid & 31] = h0[(size_t)b * UU + tid];
  __syncthreads();

  if (w < 4) {
    // ----- z/r role -----
    const int u0 = w * 64 + ug * 4;          // output columns u0..u0+3 of [0,256)
    float4 wz4[32];                          // wz4[i].p = rk[kq*32+i][u0+p]
#pragma unroll
    for (int i = 0; i < 32; ++i)
      wz4[i] = *(const float4*)&rk[(size_t)(kq * 32 + i) * G3U + u0];

    float4 gzA = *(const float4*)&gxb[(size_t)0 * G3U + u0];
    float4 gzB = *(const float4*)&gxb[(size_t)1 * G3U + u0];

#define ZR_STEP(CUR)                                                          \
  do {                                                                        \
    float4 acc = make_float4(0, 0, 0, 0);                                     \
    _Pragma("unroll") for (int i = 0; i < 8; ++i) {                           \
      float4 hv = *(const float4*)&h_buf[kq][i * 4];                          \
      acc = fma4(hv.x, wz4[i * 4 + 0], acc);                                  \
      acc = fma4(hv.y, wz4[i * 4 + 1], acc);                                  \
      acc = fma4(hv.z, wz4[i * 4 + 2], acc);                                  \
      acc = fma4(hv.w, wz4[i * 4 + 3], acc);                                  \
    }                                                                         \
    acc.x = quad_sum(acc.x);                                                  \
    acc.y = quad_sum(acc.y);                                                  \
    acc.z = quad_sum(acc.z);                                                  \
    acc.w = quad_sum(acc.w);                                                  \
    float g0 = sigmoidf_(acc.x + (CUR).x);                                    \
    float g1 = sigmoidf_(acc.y + (CUR).y);                                    \
    float g2 = sigmoidf_(acc.z + (CUR).z);                                    \
    float g3 = sigmoidf_(acc.w + (CUR).w);                                    \
    if (w < 2) {                                                              \
      if (kq == 0) *(float4*)&zbuf[u0] = make_float4(g0, g1, g2, g3);         \
    } else if (kq == 0) {                                                     \
      const int hidx = u0 - 128;                                              \
      float4 hv = *(const float4*)&h_buf[hidx >> 5][hidx & 31];               \
      *(float4*)&rh_buf[hidx >> 5][hidx & 31] =                               \
          make_float4(g0 * hv.x, g1 * hv.y, g2 * hv.z, g3 * hv.w);            \
    }                                                                         \
    __syncthreads(); /* B1: rh/z published */                                 \
    __syncthreads(); /* B2: h updated by hh waves */                          \
  } while (0)

    for (int t = 0; t < TT; t += 2) {
      float4 c0 = gzA;
      if (t + 2 < TT) gzA = *(const float4*)&gxb[(size_t)(t + 2) * G3U + u0];
      ZR_STEP(c0);
      float4 c1 = gzB;
      if (t + 3 < TT) gzB = *(const float4*)&gxb[(size_t)(t + 3) * G3U + u0];
      ZR_STEP(c1);
    }
#undef ZR_STEP
  } else {
    // ----- hh role -----
    const int w2 = w - 4;
    const int u2 = w2 * 32 + ug * 2;         // output columns u2,u2+1 of [0,128)
    float2 wh2[32];                          // wh2[i].p = rk[kq*32+i][256+u2+p]
#pragma unroll
    for (int i = 0; i < 32; ++i)
      wh2[i] = *(const float2*)&rk[(size_t)(kq * 32 + i) * G3U + 256 + u2];

    float2 ghA = *(const float2*)&gxb[(size_t)0 * G3U + 256 + u2];
    float2 ghB = *(const float2*)&gxb[(size_t)1 * G3U + 256 + u2];

#define HH_STEP(T_IDX, CURH)                                                  \
  do {                                                                        \
    __syncthreads(); /* B1: wait for rh/z */                                  \
    float2 acc = make_float2(0, 0);                                           \
    _Pragma("unroll") for (int i = 0; i < 8; ++i) {                           \
      float4 rv = *(const float4*)&rh_buf[kq][i * 4];                         \
      acc = fma2(rv.x, wh2[i * 4 + 0], acc);                                  \
      acc = fma2(rv.y, wh2[i * 4 + 1], acc);                                  \
      acc = fma2(rv.z, wh2[i * 4 + 2], acc);                                  \
      acc = fma2(rv.w, wh2[i * 4 + 3], acc);                                  \
    }                                                                         \
    acc.x = quad_sum(acc.x);                                                  \
    acc.y = quad_sum(acc.y);                                                  \
    float hh0 = tanhf_(acc.x + (CURH).x);                                     \
    float hh1 = tanhf_(acc.y + (CURH).y);                                     \
    float2 zz = *(const float2*)&zbuf[u2];                                    \
    float2 hold = *(const float2*)&h_buf[u2 >> 5][u2 & 31];                   \
    float hn0 = zz.x * hold.x + (1.0f - zz.x) * hh0;                          \
    float hn1 = zz.y * hold.y + (1.0f - zz.y) * hh1;                          \
    if (kq == 0) {                                                            \
      *(float2*)&h_buf[u2 >> 5][u2 & 31] = make_float2(hn0, hn1);             \
      *(float2*)&outb[(size_t)(T_IDX)*UU + u2] = make_float2(hn0, hn1);       \
    }                                                                         \
    __syncthreads(); /* B2: h published */                                    \
  } while (0)

    for (int t = 0; t < TT; t += 2) {
      float2 c0 = ghA;
      if (t + 2 < TT) ghA = *(const float2*)&gxb[(size_t)(t + 2) * G3U + 256 + u2];
      HH_STEP(t, c0);
      float2 c1 = ghB;
      if (t + 3 < TT) ghB = *(const float2*)&gxb[(size_t)(t + 3) * G3U + 256 + u2];
      HH_STEP(t + 1, c1);
    }
#undef HH_STEP
  }
}

extern "C" void kernel_launch(void* const* d_in, const int* in_sizes, int n_in,
                              void* d_out, int out_size, void* d_ws, size_t ws_size,
                              hipStream_t stream) {
  const float* x = (const float*)d_in[0];
  const float* kern = (const float*)d_in[1];
  const float* rk = (const float*)d_in[2];
  const float* akern = (const float*)d_in[3];
  // d_in[4] attention_w, d_in[5] attention_u, d_in[7] attention_b, d_in[8] attention_v:
  // mathematically dead (softmax over singleton axis == 1, so z_hat == x_t).
  const float* bias = (const float*)d_in[6];
  const float* h0 = (const float*)d_in[9];
  float* out = (float*)d_out;
  float* gx = (float*)d_ws;  // [NROW][384] fp32 = 393,216,000 bytes

  gx_kernel<<<dim3(NROW / 64, G3U / 64), 256, 0, stream>>>(x, kern, akern, bias, gx);
  gru_rec<<<dim3(BB), 512, 0, stream>>>(gx, rk, h0, out);
}

// Round 2
// 1977.272 us; speedup vs baseline: 1.1706x; 1.1706x over previous
//
#include <hip/hip_runtime.h>

#define TT 2000
#define BB 128
#define DD 64
#define UU 128
#define G3U 384          // 3*U
#define NROW (BB * TT)   // 256000 rows of x / gx

// ---------- helpers ----------
__device__ __forceinline__ float4 fma4(float s, float4 w, float4 a) {
  a.x = fmaf(s, w.x, a.x);
  a.y = fmaf(s, w.y, a.y);
  a.z = fmaf(s, w.z, a.z);
  a.w = fmaf(s, w.w, a.w);
  return a;
}
// packed dual-FP32 FMA: acc.{x,y} += a.{x,y} * b.{x,y}
__device__ __forceinline__ void pk_fma(float2& acc, float2 a, float2 b) {
  asm("v_pk_fma_f32 %0, %1, %2, %0" : "+v"(acc) : "v"(a), "v"(b));
}
// sum across the 4 lanes of a quad via DPP quad_perm (VALU pipe, no LDS)
__device__ __forceinline__ float quad_sum(float v) {
  v += __int_as_float(__builtin_amdgcn_update_dpp(0, __float_as_int(v), 0xB1, 0xF, 0xF, true)); // swap lane^1
  v += __int_as_float(__builtin_amdgcn_update_dpp(0, __float_as_int(v), 0x4E, 0xF, 0xF, true)); // swap lane^2
  return v;
}
__device__ __forceinline__ float sigmoidf_(float v) { return 1.0f / (1.0f + __expf(-v)); }
__device__ __forceinline__ float tanhf_(float v) {
  float a = fabsf(v);
  float e = __expf(-2.0f * a);
  float r = (1.0f - e) / (1.0f + e);   // in [0,1), no NaN for large |v|
  return copysignf(r, v);
}

// ---------- prologue: gx[r][c] = sum_k x[r][k]*(kern[k][c]+akern[k][c]) + bias[c] ----------
__global__ __launch_bounds__(256, 2)
void gx_kernel(const float* __restrict__ x, const float* __restrict__ kern,
               const float* __restrict__ akern, const float* __restrict__ bias,
               float* __restrict__ gx) {
  __shared__ __align__(16) float xT[64][68];
  __shared__ __align__(16) float Ws[64][68];
  const int r0 = blockIdx.x * 64;
  const int c0 = blockIdx.y * 64;
  const int tid = threadIdx.x;

  {
    const int row = tid >> 2;
    const int kb = (tid & 3) * 16;
#pragma unroll
    for (int i = 0; i < 4; ++i) {
      float4 v = *(const float4*)&x[(size_t)(r0 + row) * DD + kb + i * 4];
      xT[kb + i * 4 + 0][row] = v.x;
      xT[kb + i * 4 + 1][row] = v.y;
      xT[kb + i * 4 + 2][row] = v.z;
      xT[kb + i * 4 + 3][row] = v.w;
    }
    const int kk = tid >> 2;
    const int jb = (tid & 3) * 16;
#pragma unroll
    for (int i = 0; i < 4; ++i) {
      const size_t off = (size_t)kk * G3U + c0 + jb + i * 4;
      float4 a = *(const float4*)&kern[off];
      float4 c = *(const float4*)&akern[off];
      *(float4*)&Ws[kk][jb + i * 4] = make_float4(a.x + c.x, a.y + c.y, a.z + c.z, a.w + c.w);
    }
  }
  __syncthreads();

  const int tx = tid & 15, ty = tid >> 4;
  float4 acc0 = make_float4(0, 0, 0, 0), acc1 = acc0, acc2 = acc0, acc3 = acc0;
#pragma unroll
  for (int k = 0; k < 64; ++k) {
    float4 wv = *(const float4*)&Ws[k][tx * 4];
    float4 xv = *(const float4*)&xT[k][ty * 4];
    acc0 = fma4(xv.x, wv, acc0);
    acc1 = fma4(xv.y, wv, acc1);
    acc2 = fma4(xv.z, wv, acc2);
    acc3 = fma4(xv.w, wv, acc3);
  }
  float4 bv = *(const float4*)&bias[c0 + tx * 4];
  acc0.x += bv.x; acc0.y += bv.y; acc0.z += bv.z; acc0.w += bv.w;
  acc1.x += bv.x; acc1.y += bv.y; acc1.z += bv.z; acc1.w += bv.w;
  acc2.x += bv.x; acc2.y += bv.y; acc2.z += bv.z; acc2.w += bv.w;
  acc3.x += bv.x; acc3.y += bv.y; acc3.z += bv.z; acc3.w += bv.w;
  float* g0 = &gx[(size_t)(r0 + ty * 4) * G3U + c0 + tx * 4];
  *(float4*)(g0 + 0 * G3U) = acc0;
  *(float4*)(g0 + 1 * G3U) = acc1;
  *(float4*)(g0 + 2 * G3U) = acc2;
  *(float4*)(g0 + 3 * G3U) = acc3;
}

// ---------- recurrence ----------
// One block per batch row, 512 threads = 8 waves, ALL waves work in BOTH phases.
// Lane mapping: g = tid>>2 (0..127 output group), kq = tid&3 (k-chunk of 32).
// Phase 1: group g owns z/r columns {2g, 2g+1} of [0,256): waves 0-3 -> z, 4-7 -> r.
// Phase 2: group g owns hh column g of [0,128).
// Quad partials combined via DPP quad_sum; packed v_pk_fma_f32 throughout.
__global__ __launch_bounds__(512, 2)
void gru_rec(const float* __restrict__ gx, const float* __restrict__ rk,
             const float* __restrict__ h0, float* __restrict__ out) {
  const int b = blockIdx.x;
  const int tid = threadIdx.x;
  const int g = tid >> 2;        // 0..127
  const int kq = tid & 3;        // 0..3
  const int u0 = g * 2;          // phase-1 columns u0, u0+1
  const int u2 = g;              // phase-2 column
  const int k0 = kq * 32;
  const bool isR = (u0 >= 128);  // wave-uniform (waves 4-7)
  const int hidx = isR ? (u0 - 128) : 0;

  // chunked bank-staggered buffers: value k lives at [k>>5][k&31]
  __shared__ __align__(16) float h_buf[4][40];
  __shared__ __align__(16) float rh_buf[4][40];
  __shared__ __align__(16) float zbuf[128];

  const float* gxb = gx + (size_t)b * TT * G3U;
  float* outb = out + (size_t)b * TT * UU;

  // weights in VGPRs, packed along k:
  //  wA[i] = (rk[k0+2i][u0],     rk[k0+2i+1][u0])
  //  wB[i] = (rk[k0+2i][u0+1],   rk[k0+2i+1][u0+1])
  //  wH[i] = (rk[k0+2i][256+u2], rk[k0+2i+1][256+u2])
  float2 wA[16], wB[16], wH[16];
#pragma unroll
  for (int i = 0; i < 16; ++i) {
    const float* r0p = rk + (size_t)(k0 + 2 * i) * G3U;
    const float* r1p = rk + (size_t)(k0 + 2 * i + 1) * G3U;
    wA[i] = make_float2(r0p[u0], r1p[u0]);
    wB[i] = make_float2(r0p[u0 + 1], r1p[u0 + 1]);
    wH[i] = make_float2(r0p[256 + u2], r1p[256 + u2]);
  }

  if (tid < UU) h_buf[tid >> 5][tid & 31] = h0[(size_t)b * UU + tid];
  __syncthreads();

  float2 gzA = *(const float2*)&gxb[(size_t)0 * G3U + u0];
  float2 gzB = *(const float2*)&gxb[(size_t)1 * G3U + u0];
  float ghA = gxb[(size_t)0 * G3U + 256 + u2];
  float ghB = gxb[(size_t)1 * G3U + 256 + u2];

#define STEP(T_IDX, GZ, GH)                                                   \
  do {                                                                        \
    float2 curz = (GZ);                                                       \
    float curh = (GH);                                                        \
    if ((T_IDX) + 2 < TT) {                                                   \
      (GZ) = *(const float2*)&gxb[(size_t)((T_IDX) + 2) * G3U + u0];          \
      (GH) = gxb[(size_t)((T_IDX) + 2) * G3U + 256 + u2];                     \
    }                                                                         \
    /* phase 1: z/r gates, 32 pk_fma per lane */                              \
    float2 acc0 = make_float2(0.f, 0.f), acc1 = acc0;                         \
    _Pragma("unroll") for (int ii = 0; ii < 8; ++ii) {                        \
      float4 hv = *(const float4*)&h_buf[kq][ii * 4];                         \
      float2 hlo = make_float2(hv.x, hv.y);                                   \
      float2 hhi = make_float2(hv.z, hv.w);                                   \
      pk_fma(acc0, hlo, wA[2 * ii]);                                          \
      pk_fma(acc1, hlo, wB[2 * ii]);                                          \
      pk_fma(acc0, hhi, wA[2 * ii + 1]);                                      \
      pk_fma(acc1, hhi, wB[2 * ii + 1]);                                      \
    }                                                                         \
    float s0 = quad_sum(acc0.x + acc0.y);                                     \
    float s1 = quad_sum(acc1.x + acc1.y);                                     \
    float g0 = sigmoidf_(s0 + curz.x);                                        \
    float g1 = sigmoidf_(s1 + curz.y);                                        \
    if (kq == 0) {                                                            \
      if (!isR) {                                                             \
        *(float2*)&zbuf[u0] = make_float2(g0, g1);                            \
      } else {                                                                \
        float2 hv = *(const float2*)&h_buf[hidx >> 5][hidx & 31];             \
        *(float2*)&rh_buf[hidx >> 5][hidx & 31] =                             \
            make_float2(g0 * hv.x, g1 * hv.y);                                \
      }                                                                       \
    }                                                                         \
    __syncthreads(); /* B1: z, r*h published */                               \
    /* phase 2: hh candidate, 16 pk_fma per lane */                           \
    float2 acc = make_float2(0.f, 0.f);                                       \
    _Pragma("unroll") for (int ii = 0; ii < 8; ++ii) {                        \
      float4 rv = *(const float4*)&rh_buf[kq][ii * 4];                        \
      pk_fma(acc, make_float2(rv.x, rv.y), wH[2 * ii]);                       \
      pk_fma(acc, make_float2(rv.z, rv.w), wH[2 * ii + 1]);                   \
    }                                                                         \
    float sh = quad_sum(acc.x + acc.y);                                       \
    float hh = tanhf_(sh + curh);                                             \
    float zz = zbuf[u2];                                                      \
    float hold = h_buf[u2 >> 5][u2 & 31];                                     \
    float hn = fmaf(zz, hold - hh, hh);                                       \
    if (kq == 0) {                                                            \
      h_buf[u2 >> 5][u2 & 31] = hn;                                           \
      outb[(size_t)(T_IDX)*UU + u2] = hn;                                     \
    }                                                                         \
    __syncthreads(); /* B2: h published */                                    \
  } while (0)

  for (int t = 0; t < TT; t += 2) {
    STEP(t, gzA, ghA);
    STEP(t + 1, gzB, ghB);
  }
#undef STEP
}

extern "C" void kernel_launch(void* const* d_in, const int* in_sizes, int n_in,
                              void* d_out, int out_size, void* d_ws, size_t ws_size,
                              hipStream_t stream) {
  const float* x = (const float*)d_in[0];
  const float* kern = (const float*)d_in[1];
  const float* rk = (const float*)d_in[2];
  const float* akern = (const float*)d_in[3];
  // d_in[4] attention_w, d_in[5] attention_u, d_in[7] attention_b, d_in[8] attention_v:
  // mathematically dead (softmax over singleton axis == 1, so z_hat == x_t).
  const float* bias = (const float*)d_in[6];
  const float* h0 = (const float*)d_in[9];
  float* out = (float*)d_out;
  float* gx = (float*)d_ws;  // [NROW][384] fp32 = 393,216,000 bytes

  gx_kernel<<<dim3(NROW / 64, G3U / 64), 256, 0, stream>>>(x, kern, akern, bias, gx);
  gru_rec<<<dim3(BB), 512, 0, stream>>>(gx, rk, h0, out);
}

// Round 3
// 1856.427 us; speedup vs baseline: 1.2468x; 1.0651x over previous
//
#include <hip/hip_runtime.h>

#define TT 2000
#define BB 128
#define DD 64
#define UU 128
#define G3U 384          // 3*U
#define NROW (BB * TT)   // 256000 rows of x / gx

// ---------- helpers ----------
__device__ __forceinline__ float4 fma4(float s, float4 w, float4 a) {
  a.x = fmaf(s, w.x, a.x);
  a.y = fmaf(s, w.y, a.y);
  a.z = fmaf(s, w.z, a.z);
  a.w = fmaf(s, w.w, a.w);
  return a;
}
// packed dual-FP32 FMA: acc.{x,y} += a.{x,y} * b.{x,y}
__device__ __forceinline__ void pk_fma(float2& acc, float2 a, float2 b) {
  asm("v_pk_fma_f32 %0, %1, %2, %0" : "+v"(acc) : "v"(a), "v"(b));
}
// sum across the 4 lanes of a quad via DPP quad_perm (VALU pipe, no LDS)
__device__ __forceinline__ float quad_sum(float v) {
  v += __int_as_float(__builtin_amdgcn_update_dpp(0, __float_as_int(v), 0xB1, 0xF, 0xF, true)); // swap lane^1
  v += __int_as_float(__builtin_amdgcn_update_dpp(0, __float_as_int(v), 0x4E, 0xF, 0xF, true)); // swap lane^2
  return v;
}
__device__ __forceinline__ float sigmoidf_(float v) { return 1.0f / (1.0f + __expf(-v)); }
__device__ __forceinline__ float tanhf_(float v) {
  float a = fabsf(v);
  float e = __expf(-2.0f * a);
  float r = (1.0f - e) / (1.0f + e);   // in [0,1), no NaN for large |v|
  return copysignf(r, v);
}

// LDS-only barrier: __syncthreads() would emit s_waitcnt vmcnt(0) before
// s_barrier, draining the gx prefetch loads (HBM ~900 cyc) and the out store
// on EVERY barrier. We only need LDS visibility -> lgkmcnt(0) + raw barrier.
// sched_barrier(0) fences both sides (rule #18: compiler may hoist past
// inline-asm waitcnt otherwise).
__device__ __forceinline__ void bar_lds() {
  __builtin_amdgcn_sched_barrier(0);
  asm volatile("s_waitcnt lgkmcnt(0)" ::: "memory");
  __builtin_amdgcn_s_barrier();
  __builtin_amdgcn_sched_barrier(0);
}

// ---------- prologue: gx[r][c] = sum_k x[r][k]*(kern[k][c]+akern[k][c]) + bias[c] ----------
__global__ __launch_bounds__(256, 2)
void gx_kernel(const float* __restrict__ x, const float* __restrict__ kern,
               const float* __restrict__ akern, const float* __restrict__ bias,
               float* __restrict__ gx) {
  __shared__ __align__(16) float xT[64][68];
  __shared__ __align__(16) float Ws[64][68];
  const int r0 = blockIdx.x * 64;
  const int c0 = blockIdx.y * 64;
  const int tid = threadIdx.x;

  {
    const int row = tid >> 2;
    const int kb = (tid & 3) * 16;
#pragma unroll
    for (int i = 0; i < 4; ++i) {
      float4 v = *(const float4*)&x[(size_t)(r0 + row) * DD + kb + i * 4];
      xT[kb + i * 4 + 0][row] = v.x;
      xT[kb + i * 4 + 1][row] = v.y;
      xT[kb + i * 4 + 2][row] = v.z;
      xT[kb + i * 4 + 3][row] = v.w;
    }
    const int kk = tid >> 2;
    const int jb = (tid & 3) * 16;
#pragma unroll
    for (int i = 0; i < 4; ++i) {
      const size_t off = (size_t)kk * G3U + c0 + jb + i * 4;
      float4 a = *(const float4*)&kern[off];
      float4 c = *(const float4*)&akern[off];
      *(float4*)&Ws[kk][jb + i * 4] = make_float4(a.x + c.x, a.y + c.y, a.z + c.z, a.w + c.w);
    }
  }
  __syncthreads();

  const int tx = tid & 15, ty = tid >> 4;
  float4 acc0 = make_float4(0, 0, 0, 0), acc1 = acc0, acc2 = acc0, acc3 = acc0;
#pragma unroll
  for (int k = 0; k < 64; ++k) {
    float4 wv = *(const float4*)&Ws[k][tx * 4];
    float4 xv = *(const float4*)&xT[k][ty * 4];
    acc0 = fma4(xv.x, wv, acc0);
    acc1 = fma4(xv.y, wv, acc1);
    acc2 = fma4(xv.z, wv, acc2);
    acc3 = fma4(xv.w, wv, acc3);
  }
  float4 bv = *(const float4*)&bias[c0 + tx * 4];
  acc0.x += bv.x; acc0.y += bv.y; acc0.z += bv.z; acc0.w += bv.w;
  acc1.x += bv.x; acc1.y += bv.y; acc1.z += bv.z; acc1.w += bv.w;
  acc2.x += bv.x; acc2.y += bv.y; acc2.z += bv.z; acc2.w += bv.w;
  acc3.x += bv.x; acc3.y += bv.y; acc3.z += bv.z; acc3.w += bv.w;
  float* g0 = &gx[(size_t)(r0 + ty * 4) * G3U + c0 + tx * 4];
  *(float4*)(g0 + 0 * G3U) = acc0;
  *(float4*)(g0 + 1 * G3U) = acc1;
  *(float4*)(g0 + 2 * G3U) = acc2;
  *(float4*)(g0 + 3 * G3U) = acc3;
}

// ---------- recurrence ----------
// One block per batch row, 512 threads = 8 waves, ALL waves work in BOTH phases.
// Lane mapping: g = tid>>2 (0..127 output group), kq = tid&3 (k-chunk of 32).
// Phase 1: group g owns z/r columns {2g, 2g+1} of [0,256): waves 0-3 -> z, 4-7 -> r.
// Phase 2: group g owns hh column g of [0,128).
// Quad partials combined via DPP quad_sum; packed v_pk_fma_f32 throughout.
// Barriers are LDS-only (bar_lds) so the 4-step-deep gx prefetch and the out
// stores stay in flight across steps.
__global__ __launch_bounds__(512, 2)
void gru_rec(const float* __restrict__ gx, const float* __restrict__ rk,
             const float* __restrict__ h0, float* __restrict__ out) {
  const int b = blockIdx.x;
  const int tid = threadIdx.x;
  const int g = tid >> 2;        // 0..127
  const int kq = tid & 3;        // 0..3
  const int u0 = g * 2;          // phase-1 columns u0, u0+1
  const int u2 = g;              // phase-2 column
  const int k0 = kq * 32;
  const bool isR = (u0 >= 128);  // wave-uniform (waves 4-7)
  const int hidx = isR ? (u0 - 128) : 0;

  // chunked bank-staggered buffers: value k lives at [k>>5][k&31]
  __shared__ __align__(16) float h_buf[4][40];
  __shared__ __align__(16) float rh_buf[4][40];
  __shared__ __align__(16) float zbuf[128];

  const float* gxb = gx + (size_t)b * TT * G3U;
  float* outb = out + (size_t)b * TT * UU;

  // weights in VGPRs, packed along k:
  //  wA[i] = (rk[k0+2i][u0],     rk[k0+2i+1][u0])
  //  wB[i] = (rk[k0+2i][u0+1],   rk[k0+2i+1][u0+1])
  //  wH[i] = (rk[k0+2i][256+u2], rk[k0+2i+1][256+u2])
  float2 wA[16], wB[16], wH[16];
#pragma unroll
  for (int i = 0; i < 16; ++i) {
    const float* r0p = rk + (size_t)(k0 + 2 * i) * G3U;
    const float* r1p = rk + (size_t)(k0 + 2 * i + 1) * G3U;
    wA[i] = make_float2(r0p[u0], r1p[u0]);
    wB[i] = make_float2(r0p[u0 + 1], r1p[u0 + 1]);
    wH[i] = make_float2(r0p[256 + u2], r1p[256 + u2]);
  }

  if (tid < UU) h_buf[tid >> 5][tid & 31] = h0[(size_t)b * UU + tid];

  // 4-deep prefetch ring (named regs; rule #20: no runtime indexing)
  float2 gz0 = *(const float2*)&gxb[(size_t)0 * G3U + u0];
  float2 gz1 = *(const float2*)&gxb[(size_t)1 * G3U + u0];
  float2 gz2 = *(const float2*)&gxb[(size_t)2 * G3U + u0];
  float2 gz3 = *(const float2*)&gxb[(size_t)3 * G3U + u0];
  float gh0 = gxb[(size_t)0 * G3U + 256 + u2];
  float gh1 = gxb[(size_t)1 * G3U + 256 + u2];
  float gh2 = gxb[(size_t)2 * G3U + 256 + u2];
  float gh3 = gxb[(size_t)3 * G3U + 256 + u2];

  bar_lds();

#define STEP(T_IDX, GZ, GH)                                                   \
  do {                                                                        \
    float2 curz = (GZ);                                                       \
    float curh = (GH);                                                        \
    if ((T_IDX) + 4 < TT) {                                                   \
      (GZ) = *(const float2*)&gxb[(size_t)((T_IDX) + 4) * G3U + u0];          \
      (GH) = gxb[(size_t)((T_IDX) + 4) * G3U + 256 + u2];                     \
    }                                                                         \
    /* phase 1: z/r gates, 32 pk_fma per lane */                              \
    float2 acc0 = make_float2(0.f, 0.f), acc1 = acc0;                         \
    _Pragma("unroll") for (int ii = 0; ii < 8; ++ii) {                        \
      float4 hv = *(const float4*)&h_buf[kq][ii * 4];                         \
      float2 hlo = make_float2(hv.x, hv.y);                                   \
      float2 hhi = make_float2(hv.z, hv.w);                                   \
      pk_fma(acc0, hlo, wA[2 * ii]);                                          \
      pk_fma(acc1, hlo, wB[2 * ii]);                                          \
      pk_fma(acc0, hhi, wA[2 * ii + 1]);                                      \
      pk_fma(acc1, hhi, wB[2 * ii + 1]);                                      \
    }                                                                         \
    float s0 = quad_sum(acc0.x + acc0.y);                                     \
    float s1 = quad_sum(acc1.x + acc1.y);                                     \
    float g0 = sigmoidf_(s0 + curz.x);                                        \
    float g1 = sigmoidf_(s1 + curz.y);                                        \
    if (kq == 0) {                                                            \
      if (!isR) {                                                             \
        *(float2*)&zbuf[u0] = make_float2(g0, g1);                            \
      } else {                                                                \
        float2 hv = *(const float2*)&h_buf[hidx >> 5][hidx & 31];             \
        *(float2*)&rh_buf[hidx >> 5][hidx & 31] =                             \
            make_float2(g0 * hv.x, g1 * hv.y);                                \
      }                                                                       \
    }                                                                         \
    bar_lds(); /* B1: z, r*h published */                                     \
    /* phase 2: hh candidate, 16 pk_fma per lane */                           \
    float2 acc = make_float2(0.f, 0.f);                                       \
    _Pragma("unroll") for (int ii = 0; ii < 8; ++ii) {                        \
      float4 rv = *(const float4*)&rh_buf[kq][ii * 4];                        \
      pk_fma(acc, make_float2(rv.x, rv.y), wH[2 * ii]);                       \
      pk_fma(acc, make_float2(rv.z, rv.w), wH[2 * ii + 1]);                   \
    }                                                                         \
    float sh = quad_sum(acc.x + acc.y);                                       \
    float hh = tanhf_(sh + curh);                                             \
    float zz = zbuf[u2];                                                      \
    float hold = h_buf[u2 >> 5][u2 & 31];                                     \
    float hn = fmaf(zz, hold - hh, hh);                                       \
    if (kq == 0) {                                                            \
      h_buf[u2 >> 5][u2 & 31] = hn;                                           \
      outb[(size_t)(T_IDX)*UU + u2] = hn;                                     \
    }                                                                         \
    bar_lds(); /* B2: h published */                                          \
  } while (0)

  for (int t = 0; t < TT; t += 4) {
    STEP(t + 0, gz0, gh0);
    STEP(t + 1, gz1, gh1);
    STEP(t + 2, gz2, gh2);
    STEP(t + 3, gz3, gh3);
  }
#undef STEP
}

extern "C" void kernel_launch(void* const* d_in, const int* in_sizes, int n_in,
                              void* d_out, int out_size, void* d_ws, size_t ws_size,
                              hipStream_t stream) {
  const float* x = (const float*)d_in[0];
  const float* kern = (const float*)d_in[1];
  const float* rk = (const float*)d_in[2];
  const float* akern = (const float*)d_in[3];
  // d_in[4] attention_w, d_in[5] attention_u, d_in[7] attention_b, d_in[8] attention_v:
  // mathematically dead (softmax over singleton axis == 1, so z_hat == x_t).
  const float* bias = (const float*)d_in[6];
  const float* h0 = (const float*)d_in[9];
  float* out = (float*)d_out;
  float* gx = (float*)d_ws;  // [NROW][384] fp32 = 393,216,000 bytes

  gx_kernel<<<dim3(NROW / 64, G3U / 64), 256, 0, stream>>>(x, kern, akern, bias, gx);
  gru_rec<<<dim3(BB), 512, 0, stream>>>(gx, rk, h0, out);
}

// Round 5
// 1790.174 us; speedup vs baseline: 1.2930x; 1.0370x over previous
//
#include <hip/hip_runtime.h>

#define TT 2000
#define BB 128
#define DD 64
#define UU 128
#define G3U 384          // 3*U
#define NROW (BB * TT)   // 256000 rows of x / gx

// ---------- helpers ----------
__device__ __forceinline__ float4 fma4(float s, float4 w, float4 a) {
  a.x = fmaf(s, w.x, a.x);
  a.y = fmaf(s, w.y, a.y);
  a.z = fmaf(s, w.z, a.z);
  a.w = fmaf(s, w.w, a.w);
  return a;
}
// packed dual-FP32 FMA: acc.{x,y} += a.{x,y} * b.{x,y}
__device__ __forceinline__ void pk_fma(float2& acc, float2 a, float2 b) {
  asm("v_pk_fma_f32 %0, %1, %2, %0" : "+v"(acc) : "v"(a), "v"(b));
}
// DPP ctrl must be a syntactic constant at the builtin call -> template param.
template <int CTRL>
__device__ __forceinline__ float dpp_mov(float v) {
  return __int_as_float(__builtin_amdgcn_update_dpp(0, __float_as_int(v), CTRL, 0xF, 0xF, true));
}
// sum a packed pair then reduce across the 8 lanes of the group
// (lanes 8g..8g+7): xor1, xor2 (quad_perm), then row_half_mirror (i -> 7-i
// within each half-row of 8, which crosses the two quads). All 8 lanes end
// holding the full sum.
__device__ __forceinline__ float red8(float2 a) {
  float v = a.x + a.y;
  v += dpp_mov<0xB1>(v);   // quad_perm [1,0,3,2]  : lane ^ 1
  v += dpp_mov<0x4E>(v);   // quad_perm [2,3,0,1]  : lane ^ 2
  v += dpp_mov<0x141>(v);  // row_half_mirror      : other quad within 8
  return v;
}
// sigmoid via exp2: 1 / (1 + 2^(-x*log2e))  -- saturates correctly at +-inf
__device__ __forceinline__ float sig_(float v) {
  float e = __builtin_amdgcn_exp2f(-1.442695041f * v);
  return __builtin_amdgcn_rcpf(1.0f + e);
}
// tanh(x) = 2*sigmoid(2x) - 1 = 2/(1+2^(-2x*log2e)) - 1 ; exact at +-inf
__device__ __forceinline__ float tanh_(float v) {
  float e = __builtin_amdgcn_exp2f(-2.885390082f * v);
  float r = __builtin_amdgcn_rcpf(1.0f + e);
  return fmaf(2.0f, r, -1.0f);
}

// LDS-only barrier: avoid the vmcnt(0) drain __syncthreads() would emit.
// asm "memory" clobber fences memory ops on the producer side; the trailing
// sched_barrier(0) stops post-barrier LDS reads being hoisted above s_barrier
// (s_barrier alone is not a compiler memory fence).
__device__ __forceinline__ void bar_lds() {
  __builtin_amdgcn_sched_barrier(0);
  asm volatile("s_waitcnt lgkmcnt(0)" ::: "memory");
  __builtin_amdgcn_s_barrier();
  __builtin_amdgcn_sched_barrier(0);
}

// ---------- prologue: gx[r][c] = sum_k x[r][k]*(kern[k][c]+akern[k][c]) + bias[c] ----------
__global__ __launch_bounds__(256, 2)
void gx_kernel(const float* __restrict__ x, const float* __restrict__ kern,
               const float* __restrict__ akern, const float* __restrict__ bias,
               float* __restrict__ gx) {
  __shared__ __align__(16) float xT[64][68];
  __shared__ __align__(16) float Ws[64][68];
  const int r0 = blockIdx.x * 64;
  const int c0 = blockIdx.y * 64;
  const int tid = threadIdx.x;

  {
    const int row = tid >> 2;
    const int kb = (tid & 3) * 16;
#pragma unroll
    for (int i = 0; i < 4; ++i) {
      float4 v = *(const float4*)&x[(size_t)(r0 + row) * DD + kb + i * 4];
      xT[kb + i * 4 + 0][row] = v.x;
      xT[kb + i * 4 + 1][row] = v.y;
      xT[kb + i * 4 + 2][row] = v.z;
      xT[kb + i * 4 + 3][row] = v.w;
    }
    const int kk = tid >> 2;
    const int jb = (tid & 3) * 16;
#pragma unroll
    for (int i = 0; i < 4; ++i) {
      const size_t off = (size_t)kk * G3U + c0 + jb + i * 4;
      float4 a = *(const float4*)&kern[off];
      float4 c = *(const float4*)&akern[off];
      *(float4*)&Ws[kk][jb + i * 4] = make_float4(a.x + c.x, a.y + c.y, a.z + c.z, a.w + c.w);
    }
  }
  __syncthreads();

  const int tx = tid & 15, ty = tid >> 4;
  float4 acc0 = make_float4(0, 0, 0, 0), acc1 = acc0, acc2 = acc0, acc3 = acc0;
#pragma unroll
  for (int k = 0; k < 64; ++k) {
    float4 wv = *(const float4*)&Ws[k][tx * 4];
    float4 xv = *(const float4*)&xT[k][ty * 4];
    acc0 = fma4(xv.x, wv, acc0);
    acc1 = fma4(xv.y, wv, acc1);
    acc2 = fma4(xv.z, wv, acc2);
    acc3 = fma4(xv.w, wv, acc3);
  }
  float4 bv = *(const float4*)&bias[c0 + tx * 4];
  acc0.x += bv.x; acc0.y += bv.y; acc0.z += bv.z; acc0.w += bv.w;
  acc1.x += bv.x; acc1.y += bv.y; acc1.z += bv.z; acc1.w += bv.w;
  acc2.x += bv.x; acc2.y += bv.y; acc2.z += bv.z; acc2.w += bv.w;
  acc3.x += bv.x; acc3.y += bv.y; acc3.z += bv.z; acc3.w += bv.w;
  float* g0 = &gx[(size_t)(r0 + ty * 4) * G3U + c0 + tx * 4];
  *(float4*)(g0 + 0 * G3U) = acc0;
  *(float4*)(g0 + 1 * G3U) = acc1;
  *(float4*)(g0 + 2 * G3U) = acc2;
  *(float4*)(g0 + 3 * G3U) = acc3;
}

// ---------- recurrence ----------
// One block per batch row, 512 threads = 8 waves.
// Group = 8 lanes: g = tid>>3 (0..63), j = tid&7 owns k-slice [16j, 16j+16).
// Group g owns columns: z {2g,2g+1}, r {128+2g,128+2g+1}, hh {2g,2g+1}.
//   -> z stays in registers across B1 (no zbuf), only rh and h go through LDS.
// LDS traffic halved vs k-chunk-32: 4 ds_read_b128 per lane per phase.
// h double-buffered by step parity (race-free read of old h for rh/blend).
// LDS rows stride 36 floats (144B): the 8 chunk reads land on all 32 banks
// exactly once -> zero conflict; same-address lanes broadcast.
__global__ __launch_bounds__(512, 2)
void gru_rec(const float* __restrict__ gx, const float* __restrict__ rk,
             const float* __restrict__ h0, float* __restrict__ out) {
  const int b = blockIdx.x;
  const int tid = threadIdx.x;
  const int g = tid >> 3;        // 0..63
  const int j = tid & 7;         // k-slice index
  const int kbase = j * 16;

  __shared__ __align__(16) float hb[2][8][36];   // h, value k at [p][k>>4][k&15]
  __shared__ __align__(16) float rhb[8][36];     // r*h, same layout

  const float* gxb = gx + (size_t)b * TT * G3U;
  float* outb = out + (size_t)b * TT * UU;

  // weights in VGPRs, packed along k:
  //   wZ[c][m] = (rk[kbase+2m][2g+c],     rk[kbase+2m+1][2g+c])
  //   wR[c][m] = (rk[kbase+2m][128+2g+c], rk[kbase+2m+1][128+2g+c])
  //   wH[c][m] = (rk[kbase+2m][256+2g+c], rk[kbase+2m+1][256+2g+c])
  float2 wZ[2][8], wR[2][8], wH[2][8];
#pragma unroll
  for (int c = 0; c < 2; ++c) {
#pragma unroll
    for (int m = 0; m < 8; ++m) {
      const float* r0p = rk + (size_t)(kbase + 2 * m) * G3U;
      const float* r1p = rk + (size_t)(kbase + 2 * m + 1) * G3U;
      wZ[c][m] = make_float2(r0p[2 * g + c], r1p[2 * g + c]);
      wR[c][m] = make_float2(r0p[128 + 2 * g + c], r1p[128 + 2 * g + c]);
      wH[c][m] = make_float2(r0p[256 + 2 * g + c], r1p[256 + 2 * g + c]);
    }
  }

  if (tid < UU) hb[0][tid >> 4][tid & 15] = h0[(size_t)b * UU + tid];

  // 4-deep prefetch ring, 3 streams (z cols, r cols, hh cols), named regs
  float2 gz0, gz1, gz2, gz3, gr0, gr1, gr2, gr3, gh0, gh1, gh2, gh3;
  {
    const float* gp0 = gxb + 2 * g;
    gz0 = *(const float2*)(gp0 + 0 * G3U); gr0 = *(const float2*)(gp0 + 0 * G3U + 128); gh0 = *(const float2*)(gp0 + 0 * G3U + 256);
    gz1 = *(const float2*)(gp0 + 1 * G3U); gr1 = *(const float2*)(gp0 + 1 * G3U + 128); gh1 = *(const float2*)(gp0 + 1 * G3U + 256);
    gz2 = *(const float2*)(gp0 + 2 * G3U); gr2 = *(const float2*)(gp0 + 2 * G3U + 128); gh2 = *(const float2*)(gp0 + 2 * G3U + 256);
    gz3 = *(const float2*)(gp0 + 3 * G3U); gr3 = *(const float2*)(gp0 + 3 * G3U + 128); gh3 = *(const float2*)(gp0 + 3 * G3U + 256);
  }

  bar_lds();

#define STEP(T_IDX, P, GZ, GR, GH)                                            \
  do {                                                                        \
    float2 curz = (GZ), curr = (GR), curh = (GH);                             \
    if ((T_IDX) + 4 < TT) {                                                   \
      const float* gp = gxb + (size_t)((T_IDX) + 4) * G3U + 2 * g;            \
      (GZ) = *(const float2*)gp;                                              \
      (GR) = *(const float2*)(gp + 128);                                      \
      (GH) = *(const float2*)(gp + 256);                                      \
    }                                                                         \
    /* ---- phase 1: z and r for cols 2g,2g+1 ---- */                         \
    float4 ha = *(const float4*)&hb[P][j][0];                                 \
    float4 hbv = *(const float4*)&hb[P][j][4];                                \
    float4 hc = *(const float4*)&hb[P][j][8];                                 \
    float4 hd = *(const float4*)&hb[P][j][12];                                \
    float2 hg = *(const float2*)&hb[P][g >> 3][(2 * g) & 15];                 \
    float2 hp[8] = {make_float2(ha.x, ha.y),   make_float2(ha.z, ha.w),       \
                    make_float2(hbv.x, hbv.y), make_float2(hbv.z, hbv.w),     \
                    make_float2(hc.x, hc.y),   make_float2(hc.z, hc.w),       \
                    make_float2(hd.x, hd.y),   make_float2(hd.z, hd.w)};      \
    float2 aZ0, aZ1, aR0, aR1;                                                \
    aZ0 = aZ1 = aR0 = aR1 = make_float2(0.f, 0.f);                            \
    _Pragma("unroll") for (int m = 0; m < 8; ++m) {                           \
      pk_fma(aZ0, hp[m], wZ[0][m]);                                           \
      pk_fma(aZ1, hp[m], wZ[1][m]);                                           \
      pk_fma(aR0, hp[m], wR[0][m]);                                           \
      pk_fma(aR1, hp[m], wR[1][m]);                                           \
    }                                                                         \
    float z0 = sig_(red8(aZ0) + curz.x);                                      \
    float z1 = sig_(red8(aZ1) + curz.y);                                      \
    float r0 = sig_(red8(aR0) + curr.x);                                      \
    float r1 = sig_(red8(aR1) + curr.y);                                      \
    if (j == 0)                                                               \
      *(float2*)&rhb[g >> 3][(2 * g) & 15] = make_float2(r0 * hg.x, r1 * hg.y); \
    bar_lds(); /* B1: rh published */                                         \
    /* ---- phase 2: hh for cols 2g,2g+1; blend uses local z ---- */          \
    float4 ra = *(const float4*)&rhb[j][0];                                   \
    float4 rb_ = *(const float4*)&rhb[j][4];                                  \
    float4 rc = *(const float4*)&rhb[j][8];                                   \
    float4 rd = *(const float4*)&rhb[j][12];                                  \
    float2 rp[8] = {make_float2(ra.x, ra.y),   make_float2(ra.z, ra.w),       \
                    make_float2(rb_.x, rb_.y), make_float2(rb_.z, rb_.w),     \
                    make_float2(rc.x, rc.y),   make_float2(rc.z, rc.w),       \
                    make_float2(rd.x, rd.y),   make_float2(rd.z, rd.w)};      \
    float2 aH0, aH1;                                                          \
    aH0 = aH1 = make_float2(0.f, 0.f);                                        \
    _Pragma("unroll") for (int m = 0; m < 8; ++m) {                           \
      pk_fma(aH0, rp[m], wH[0][m]);                                           \
      pk_fma(aH1, rp[m], wH[1][m]);                                           \
    }                                                                         \
    float hh0 = tanh_(red8(aH0) + curh.x);                                    \
    float hh1 = tanh_(red8(aH1) + curh.y);                                    \
    float hn0 = fmaf(z0, hg.x - hh0, hh0);                                    \
    float hn1 = fmaf(z1, hg.y - hh1, hh1);                                    \
    if (j == 0) {                                                             \
      *(float2*)&hb[(P) ^ 1][g >> 3][(2 * g) & 15] = make_float2(hn0, hn1);   \
      *(float2*)&outb[(size_t)(T_IDX)*UU + 2 * g] = make_float2(hn0, hn1);    \
    }                                                                         \
    bar_lds(); /* B2: h published */                                          \
  } while (0)

  for (int t = 0; t < TT; t += 4) {
    STEP(t + 0, 0, gz0, gr0, gh0);
    STEP(t + 1, 1, gz1, gr1, gh1);
    STEP(t + 2, 0, gz2, gr2, gh2);
    STEP(t + 3, 1, gz3, gr3, gh3);
  }
#undef STEP
}

extern "C" void kernel_launch(void* const* d_in, const int* in_sizes, int n_in,
                              void* d_out, int out_size, void* d_ws, size_t ws_size,
                              hipStream_t stream) {
  const float* x = (const float*)d_in[0];
  const float* kern = (const float*)d_in[1];
  const float* rk = (const float*)d_in[2];
  const float* akern = (const float*)d_in[3];
  // d_in[4] attention_w, d_in[5] attention_u, d_in[7] attention_b, d_in[8] attention_v:
  // mathematically dead (softmax over singleton axis == 1, so z_hat == x_t).
  const float* bias = (const float*)d_in[6];
  const float* h0 = (const float*)d_in[9];
  float* out = (float*)d_out;
  float* gx = (float*)d_ws;  // [NROW][384] fp32 = 393,216,000 bytes

  gx_kernel<<<dim3(NROW / 64, G3U / 64), 256, 0, stream>>>(x, kern, akern, bias, gx);
  gru_rec<<<dim3(BB), 512, 0, stream>>>(gx, rk, h0, out);
}